// Round 2
// baseline (612.060 us; speedup 1.0000x reference)
//
#include <hip/hip_runtime.h>
#include <hip/hip_bf16.h>
#include <cmath>

#define HD 512
#define ND 2048
#define NB 32
#define NT 64

typedef _Float16 half8 __attribute__((ext_vector_type(8)));
typedef float f32x4 __attribute__((ext_vector_type(4)));

// XOR-swizzled LDS index for a [NT][HD] fp16 tile with physical stride 512
// (keeps total LDS at exactly 64 KB and makes 16B b128 reads bank-uniform).
__device__ __forceinline__ int xidx(int r, int c) {
  return (r << 9) + (((c >> 3) ^ (r & 7)) << 3) + (c & 7);
}

// One K=512 GEMM stage: D[64 rows][128 cols per wave] += X(64x512,f16,LDS) * Wg^T
// Wg is row-major [outdim][512] fp16, already offset to this wave's 128-row slice.
// MFMA 16x16x32_f16: A-frag = X[m=lane&15][k=quad*8+j], B-frag = Wrow[n=lane&15][k=quad*8+j].
__device__ __forceinline__ void mfma_stage(const _Float16* Xs,
                                           const _Float16* __restrict__ Wg,
                                           f32x4 (&acc)[4][8], int c, int q) {
#pragma unroll 2
  for (int ks = 0; ks < 16; ++ks) {
    half8 a[4];
#pragma unroll
    for (int mt = 0; mt < 4; ++mt) {
      int row = mt * 16 + c;
      a[mt] = *(const half8*)&Xs[(row << 9) + ((((ks << 2) + q) ^ (c & 7)) << 3)];
    }
#pragma unroll
    for (int ht = 0; ht < 8; ++ht) {
      half8 bf = *(const half8*)&Wg[(ht * 16 + c) * HD + ks * 32 + q * 8];
#pragma unroll
      for (int mt = 0; mt < 4; ++mt)
        acc[mt][ht] = __builtin_amdgcn_mfma_f32_16x16x32_f16(a[mt], bf, acc[mt][ht], 0, 0, 0);
    }
  }
}

// K1: proj_mem[b][h] = (memory[3,b,:]*masks[b,:]) . W_mem[h,:] + b_mem[h]
__global__ __launch_bounds__(256) void projmem_k(const float* __restrict__ memory,
                                                 const float* __restrict__ masks,
                                                 const float* __restrict__ W_mem,
                                                 const float* __restrict__ b_mem,
                                                 float* __restrict__ pm) {
  int b = blockIdx.x;
  int tid = threadIdx.x;
  __shared__ float lm[HD];
  for (int i = tid; i < HD; i += 256)
    lm[i] = memory[(size_t)(3 * NB + b) * HD + i] * masks[(size_t)b * HD + i];
  __syncthreads();
  for (int h = tid; h < HD; h += 256) {
    const f32x4* wr = (const f32x4*)(W_mem + (size_t)h * HD);
    const f32x4* lv = (const f32x4*)lm;
    float s = 0.f;
#pragma unroll 4
    for (int k = 0; k < 128; ++k) {
      f32x4 wv = wr[k];
      f32x4 l = lv[k];
      s += wv[0] * l[0] + wv[1] * l[1] + wv[2] * l[2] + wv[3] * l[3];
    }
    pm[(size_t)b * HD + h] = s + b_mem[h];
  }
}

// K2: convert W_kb, W_cat2 to fp16; build Weff[b][h'][h] = pm[b][h]*W_cat[h'][h] + W_cat[h'][512+h]
// rows: 0..511 -> Wkb, 512..1023 -> Wcat2, 1024..17407 -> Weff (r = rowid-1024 = b*512+h')
__global__ __launch_bounds__(256) void prep_k(const float* __restrict__ W_kb,
                                              const float* __restrict__ W_cat2,
                                              const float* __restrict__ W_cat,
                                              const float* __restrict__ pm,
                                              _Float16* __restrict__ Wkb16,
                                              _Float16* __restrict__ Wc216,
                                              _Float16* __restrict__ Weff16) {
  int rowid = blockIdx.x * 4 + (threadIdx.x >> 6);
  int lane = threadIdx.x & 63;
  int h0 = lane * 8;
  half8 o;
  if (rowid < 512) {
    const float* s = W_kb + (size_t)rowid * HD + h0;
    f32x4 v0 = *(const f32x4*)s;
    f32x4 v1 = *(const f32x4*)(s + 4);
#pragma unroll
    for (int j = 0; j < 4; ++j) { o[j] = (_Float16)v0[j]; o[4 + j] = (_Float16)v1[j]; }
    *(half8*)(Wkb16 + (size_t)rowid * HD + h0) = o;
  } else if (rowid < 1024) {
    int r = rowid - 512;
    const float* s = W_cat2 + (size_t)r * HD + h0;
    f32x4 v0 = *(const f32x4*)s;
    f32x4 v1 = *(const f32x4*)(s + 4);
#pragma unroll
    for (int j = 0; j < 4; ++j) { o[j] = (_Float16)v0[j]; o[4 + j] = (_Float16)v1[j]; }
    *(half8*)(Wc216 + (size_t)r * HD + h0) = o;
  } else {
    int r = rowid - 1024;          // r = b*512 + hp
    int b = r >> 9;
    int hp = r & 511;
    const float* wc = W_cat + (size_t)hp * (2 * HD);
    const float* pmb = pm + (size_t)b * HD;
#pragma unroll
    for (int j = 0; j < 8; ++j) {
      int h = h0 + j;
      o[j] = (_Float16)(pmb[h] * wc[h] + wc[HD + h]);
    }
    *(half8*)(Weff16 + (size_t)r * HD + h0) = o;
  }
}

// K3: fused 3-stage GEMM chain + logits. One wg per (b, 64-row n-tile). 4 waves.
__global__ __launch_bounds__(256) void fused_main(
    const float* __restrict__ know, const float* __restrict__ control,
    const _Float16* __restrict__ Wkb16, const _Float16* __restrict__ Weff16,
    const _Float16* __restrict__ Wc216,
    const float* __restrict__ b_kb, const float* __restrict__ b_cat,
    const float* __restrict__ b_cat2, const float* __restrict__ W_attn,
    float* __restrict__ logits) {
  __shared__ _Float16 X[NT * HD];   // 64 KB, XOR-swizzled [n][h]
  const int tid = threadIdx.x;
  const int w = tid >> 6;           // wave id: owns cols [128w, 128w+128)
  const int lane = tid & 63;
  const int c = lane & 15;
  const int q = lane >> 4;
  const int b = blockIdx.x >> 5;
  const int n0 = (blockIdx.x & 31) * NT;

  // stage 0: X[n][kk] = (fp16) know[b][kk][n0+n]  (transpose on the fly)
  {
    const float* kb = know + (size_t)b * HD * ND + n0;
#pragma unroll 4
    for (int it = 0; it < 32; ++it) {
      int linear = tid + 256 * it;       // over (kk, n4) with n-fast
      int kk = linear >> 4;
      int n4 = (linear & 15) << 2;
      f32x4 v = *(const f32x4*)(kb + (size_t)kk * ND + n4);
#pragma unroll
      for (int j = 0; j < 4; ++j) X[xidx(n4 + j, kk)] = (_Float16)v[j];
    }
  }
  __syncthreads();

  f32x4 acc[4][8];
  const f32x4 z4 = {0.f, 0.f, 0.f, 0.f};

  // ---- stage 1: proj_know = know_tile . Wkb^T + b_kb
#pragma unroll
  for (int mt = 0; mt < 4; ++mt)
#pragma unroll
    for (int ht = 0; ht < 8; ++ht) acc[mt][ht] = z4;
  mfma_stage(X, Wkb16 + (size_t)(w * 128) * HD, acc, c, q);
  __syncthreads();
#pragma unroll
  for (int ht = 0; ht < 8; ++ht) {
    int col = w * 128 + ht * 16 + c;
    float bias = b_kb[col];
#pragma unroll
    for (int mt = 0; mt < 4; ++mt)
#pragma unroll
      for (int r = 0; r < 4; ++r)
        X[xidx(mt * 16 + q * 4 + r, col)] = (_Float16)(acc[mt][ht][r] + bias);
  }
  __syncthreads();

  // ---- stage 2: h = elu(proj_know . Weff_b^T + b_cat)
#pragma unroll
  for (int mt = 0; mt < 4; ++mt)
#pragma unroll
    for (int ht = 0; ht < 8; ++ht) acc[mt][ht] = z4;
  mfma_stage(X, Weff16 + ((size_t)b * HD + w * 128) * HD, acc, c, q);
  __syncthreads();
#pragma unroll
  for (int ht = 0; ht < 8; ++ht) {
    int col = w * 128 + ht * 16 + c;
    float bias = b_cat[col];
#pragma unroll
    for (int mt = 0; mt < 4; ++mt)
#pragma unroll
      for (int r = 0; r < 4; ++r) {
        float v = acc[mt][ht][r] + bias;
        v = v > 0.f ? v : expm1f(v);
        X[xidx(mt * 16 + q * 4 + r, col)] = (_Float16)v;
      }
  }
  __syncthreads();

  // ---- stage 3: h2 = h . Wcat2^T + b_cat2; attn = elu(h2*ctl); logits = attn . W_attn
#pragma unroll
  for (int mt = 0; mt < 4; ++mt)
#pragma unroll
    for (int ht = 0; ht < 8; ++ht) acc[mt][ht] = z4;
  mfma_stage(X, Wc216 + (size_t)(w * 128) * HD, acc, c, q);

  float ll[4][4];
#pragma unroll
  for (int mt = 0; mt < 4; ++mt)
#pragma unroll
    for (int r = 0; r < 4; ++r) ll[mt][r] = 0.f;
  const float* ctl = control + (size_t)(3 * NB + b) * HD;
#pragma unroll
  for (int ht = 0; ht < 8; ++ht) {
    int col = w * 128 + ht * 16 + c;
    float bias = b_cat2[col];
    float cv = ctl[col];
    float wa = W_attn[col];
#pragma unroll
    for (int mt = 0; mt < 4; ++mt)
#pragma unroll
      for (int r = 0; r < 4; ++r) {
        float h2 = acc[mt][ht][r] + bias;
        float at = h2 * cv;
        at = at > 0.f ? at : expm1f(at);
        ll[mt][r] += at * wa;
      }
  }
  // reduce across the 16 col-lanes (same rows live at same q, different c)
#pragma unroll
  for (int off = 1; off <= 8; off <<= 1)
#pragma unroll
    for (int mt = 0; mt < 4; ++mt)
#pragma unroll
      for (int r = 0; r < 4; ++r) ll[mt][r] += __shfl_xor(ll[mt][r], off);

  // cross-WAVE reduction: each wave only summed its 128-col slice. Reuse X
  // (all waves are done reading it) as a [4 waves][64 rows] f32 scratch.
  __syncthreads();
  float* pr = (float*)X;
  if (c == 0) {
#pragma unroll
    for (int mt = 0; mt < 4; ++mt)
#pragma unroll
      for (int r = 0; r < 4; ++r)
        pr[w * 64 + mt * 16 + q * 4 + r] = ll[mt][r];
  }
  __syncthreads();
  if (tid < 64) {
    float s = pr[tid] + pr[64 + tid] + pr[128 + tid] + pr[192 + tid];
    logits[(size_t)b * ND + n0 + tid] = s;
  }
}

// K4: softmax over n per b (b_attn is a uniform shift -> dropped)
__global__ __launch_bounds__(256) void softmax_k(const float* __restrict__ logits,
                                                 float* __restrict__ a) {
  int b = blockIdx.x, tid = threadIdx.x;
  __shared__ float red[4];
  const float* l = logits + (size_t)b * ND;
  float* av = a + (size_t)b * ND;
  float m = -1e30f;
  for (int i = tid; i < ND; i += 256) m = fmaxf(m, l[i]);
#pragma unroll
  for (int off = 32; off; off >>= 1) m = fmaxf(m, __shfl_xor(m, off));
  if ((tid & 63) == 0) red[tid >> 6] = m;
  __syncthreads();
  float M = fmaxf(fmaxf(red[0], red[1]), fmaxf(red[2], red[3]));
  __syncthreads();
  float s = 0.f;
  for (int i = tid; i < ND; i += 256) {
    float e = expf(l[i] - M);
    av[i] = e;
    s += e;
  }
#pragma unroll
  for (int off = 32; off; off >>= 1) s += __shfl_xor(s, off);
  if ((tid & 63) == 0) red[tid >> 6] = s;
  __syncthreads();
  float inv = 1.f / (red[0] + red[1] + red[2] + red[3]);
  for (int i = tid; i < ND; i += 256) av[i] *= inv;
}

// K5: read[b][kk] = sum_n a[b][n] * know[b][kk][n]  (full f32)
__global__ __launch_bounds__(256) void read_k(const float* __restrict__ know,
                                              const float* __restrict__ a,
                                              float* __restrict__ out) {
  int b = blockIdx.x >> 7;
  int kk = ((blockIdx.x & 127) << 2) + (threadIdx.x >> 6);
  int lane = threadIdx.x & 63;
  const f32x4* kr = (const f32x4*)(know + ((size_t)b * HD + kk) * ND);
  const f32x4* ar = (const f32x4*)(a + (size_t)b * ND);
  float s = 0.f;
#pragma unroll
  for (int i = lane; i < 512; i += 64) {
    f32x4 kv = kr[i];
    f32x4 av = ar[i];
    s += kv[0] * av[0] + kv[1] * av[1] + kv[2] * av[2] + kv[3] * av[3];
  }
#pragma unroll
  for (int off = 32; off; off >>= 1) s += __shfl_xor(s, off);
  if (lane == 0) out[(size_t)b * HD + kk] = s;
}

extern "C" void kernel_launch(void* const* d_in, const int* in_sizes, int n_in,
                              void* d_out, int out_size, void* d_ws, size_t ws_size,
                              hipStream_t stream) {
  const float* memory = (const float*)d_in[0];
  const float* know = (const float*)d_in[1];
  const float* control = (const float*)d_in[2];
  const float* masks = (const float*)d_in[3];
  const float* W_mem = (const float*)d_in[4];
  const float* b_mem = (const float*)d_in[5];
  const float* W_kb = (const float*)d_in[6];
  const float* b_kb = (const float*)d_in[7];
  const float* W_cat = (const float*)d_in[8];
  const float* b_cat = (const float*)d_in[9];
  const float* W_cat2 = (const float*)d_in[10];
  const float* b_cat2 = (const float*)d_in[11];
  const float* W_attn = (const float*)d_in[12];
  // d_in[13] = b_attn: uniform logit shift, softmax-invariant.

  char* ws = (char*)d_ws;
  _Float16* Wkb16 = (_Float16*)(ws);                 //   512*512*2 = 524288
  _Float16* Wc216 = (_Float16*)(ws + 524288);        //   524288
  _Float16* Weff16 = (_Float16*)(ws + 1048576);      //   32*512*512*2 = 16777216
  float* pm = (float*)(ws + 17825792);               //   65536
  float* logits = (float*)(ws + 17891328);           //   262144
  float* aprob = (float*)(ws + 18153472);            //   262144  (total ~17.6 MB)
  float* out = (float*)d_out;

  hipLaunchKernelGGL(projmem_k, dim3(32), dim3(256), 0, stream,
                     memory, masks, W_mem, b_mem, pm);
  hipLaunchKernelGGL(prep_k, dim3(4352), dim3(256), 0, stream,
                     W_kb, W_cat2, W_cat, pm, Wkb16, Wc216, Weff16);
  hipLaunchKernelGGL(fused_main, dim3(1024), dim3(256), 0, stream,
                     know, control, Wkb16, Weff16, Wc216,
                     b_kb, b_cat, b_cat2, W_attn, logits);
  hipLaunchKernelGGL(softmax_k, dim3(32), dim3(256), 0, stream, logits, aprob);
  hipLaunchKernelGGL(read_k, dim3(4096), dim3(256), 0, stream, know, aprob, out);
}

// Round 3
// 568.514 us; speedup vs baseline: 1.0766x; 1.0766x over previous
//
#include <hip/hip_runtime.h>
#include <hip/hip_bf16.h>
#include <cmath>

#define HD 512
#define ND 2048
#define NB 32
#define NT 64

typedef _Float16 half8 __attribute__((ext_vector_type(8)));
typedef _Float16 half4 __attribute__((ext_vector_type(4)));
typedef float f32x4 __attribute__((ext_vector_type(4)));

// XOR-swizzled LDS index for a [NT][HD] fp16 tile with physical stride 512
// (keeps total LDS at exactly 64 KB; A-fragment b128 reads hit the 8-cycle
// wave64 minimum, i.e. effectively conflict-free).
__device__ __forceinline__ int xidx(int r, int c) {
  return (r << 9) + (((c >> 3) ^ (r & 7)) << 3) + (c & 7);
}

// One K=512 GEMM stage: D[64 rows][128 cols per wave] += X(64x512,f16,LDS) * Wg^T
// Wg row-major [outdim][512] fp16, offset to this wave's 128-row slice.
// B-fragments double-buffered: load ks+1's 8 frags while issuing ks's 32 MFMAs.
__device__ __forceinline__ void mfma_stage(const _Float16* Xs,
                                           const _Float16* __restrict__ Wg,
                                           f32x4 (&acc)[4][8], int c, int q) {
  const _Float16* wb = Wg + (size_t)c * HD + q * 8;
  half8 bcur[8], bnxt[8];
#pragma unroll
  for (int ht = 0; ht < 8; ++ht)
    bcur[ht] = *(const half8*)(wb + ht * (16 * HD));
#pragma unroll 2
  for (int ks = 0; ks < 15; ++ks) {
    half8 a[4];
#pragma unroll
    for (int mt = 0; mt < 4; ++mt)
      a[mt] = *(const half8*)&Xs[((mt * 16 + c) << 9) + ((((ks << 2) + q) ^ (c & 7)) << 3)];
#pragma unroll
    for (int ht = 0; ht < 8; ++ht)
      bnxt[ht] = *(const half8*)(wb + ht * (16 * HD) + (ks + 1) * 32);
#pragma unroll
    for (int ht = 0; ht < 8; ++ht)
#pragma unroll
      for (int mt = 0; mt < 4; ++mt)
        acc[mt][ht] = __builtin_amdgcn_mfma_f32_16x16x32_f16(a[mt], bcur[ht], acc[mt][ht], 0, 0, 0);
#pragma unroll
    for (int ht = 0; ht < 8; ++ht) bcur[ht] = bnxt[ht];
  }
  {  // ks = 15 (no prefetch)
    half8 a[4];
#pragma unroll
    for (int mt = 0; mt < 4; ++mt)
      a[mt] = *(const half8*)&Xs[((mt * 16 + c) << 9) + ((((15 << 2) + q) ^ (c & 7)) << 3)];
#pragma unroll
    for (int ht = 0; ht < 8; ++ht)
#pragma unroll
      for (int mt = 0; mt < 4; ++mt)
        acc[mt][ht] = __builtin_amdgcn_mfma_f32_16x16x32_f16(a[mt], bcur[ht], acc[mt][ht], 0, 0, 0);
  }
}

// K1: proj_mem[b][h] = (memory[3,b,:]*masks[b,:]) . W_mem[h,:] + b_mem[h]
__global__ __launch_bounds__(256) void projmem_k(const float* __restrict__ memory,
                                                 const float* __restrict__ masks,
                                                 const float* __restrict__ W_mem,
                                                 const float* __restrict__ b_mem,
                                                 float* __restrict__ pm) {
  int b = blockIdx.x;
  int tid = threadIdx.x;
  __shared__ float lm[HD];
  for (int i = tid; i < HD; i += 256)
    lm[i] = memory[(size_t)(3 * NB + b) * HD + i] * masks[(size_t)b * HD + i];
  __syncthreads();
  for (int h = tid; h < HD; h += 256) {
    const f32x4* wr = (const f32x4*)(W_mem + (size_t)h * HD);
    const f32x4* lv = (const f32x4*)lm;
    float s = 0.f;
#pragma unroll 4
    for (int k = 0; k < 128; ++k) {
      f32x4 wv = wr[k];
      f32x4 l = lv[k];
      s += wv[0] * l[0] + wv[1] * l[1] + wv[2] * l[2] + wv[3] * l[3];
    }
    pm[(size_t)b * HD + h] = s + b_mem[h];
  }
}

// K2: convert W_kb, W_cat2 to fp16; build Weff[b][h'][h] = pm[b][h]*W_cat[h'][h] + W_cat[h'][512+h]
__global__ __launch_bounds__(256) void prep_k(const float* __restrict__ W_kb,
                                              const float* __restrict__ W_cat2,
                                              const float* __restrict__ W_cat,
                                              const float* __restrict__ pm,
                                              _Float16* __restrict__ Wkb16,
                                              _Float16* __restrict__ Wc216,
                                              _Float16* __restrict__ Weff16) {
  int rowid = blockIdx.x * 4 + (threadIdx.x >> 6);
  int lane = threadIdx.x & 63;
  int h0 = lane * 8;
  half8 o;
  if (rowid < 512) {
    const float* s = W_kb + (size_t)rowid * HD + h0;
    f32x4 v0 = *(const f32x4*)s;
    f32x4 v1 = *(const f32x4*)(s + 4);
#pragma unroll
    for (int j = 0; j < 4; ++j) { o[j] = (_Float16)v0[j]; o[4 + j] = (_Float16)v1[j]; }
    *(half8*)(Wkb16 + (size_t)rowid * HD + h0) = o;
  } else if (rowid < 1024) {
    int r = rowid - 512;
    const float* s = W_cat2 + (size_t)r * HD + h0;
    f32x4 v0 = *(const f32x4*)s;
    f32x4 v1 = *(const f32x4*)(s + 4);
#pragma unroll
    for (int j = 0; j < 4; ++j) { o[j] = (_Float16)v0[j]; o[4 + j] = (_Float16)v1[j]; }
    *(half8*)(Wc216 + (size_t)r * HD + h0) = o;
  } else {
    int r = rowid - 1024;          // r = b*512 + hp
    int b = r >> 9;
    int hp = r & 511;
    const float* wc = W_cat + (size_t)hp * (2 * HD);
    const float* pmb = pm + (size_t)b * HD;
#pragma unroll
    for (int j = 0; j < 8; ++j) {
      int h = h0 + j;
      o[j] = (_Float16)(pmb[h] * wc[h] + wc[HD + h]);
    }
    *(half8*)(Weff16 + (size_t)r * HD + h0) = o;
  }
}

// K3: fused 3-stage GEMM chain + logits. One wg per (b, 64-row n-tile). 4 waves.
// __launch_bounds__(256,2): cap total regs at 256 so 2 waves/SIMD (2 wg/CU) fit.
__global__ __launch_bounds__(256, 2) void fused_main(
    const float* __restrict__ know, const float* __restrict__ control,
    const _Float16* __restrict__ Wkb16, const _Float16* __restrict__ Weff16,
    const _Float16* __restrict__ Wc216,
    const float* __restrict__ b_kb, const float* __restrict__ b_cat,
    const float* __restrict__ b_cat2, const float* __restrict__ W_attn,
    float* __restrict__ logits) {
  __shared__ _Float16 X[NT * HD];   // 64 KB, XOR-swizzled [n][h]
  const int tid = threadIdx.x;
  const int w = tid >> 6;           // wave id: owns cols [128w, 128w+128)
  const int lane = tid & 63;
  const int c = lane & 15;
  const int q = lane >> 4;
  const int b = blockIdx.x >> 5;
  const int n0 = (blockIdx.x & 31) * NT;

  // stage 0: X[n][kk] = (fp16) know[b][kk][n0+n] via 4x4 register-transpose,
  // packed half4 (b64) LDS writes. 2048 4x4 blocks, 8 per thread.
  {
    const float* kb = know + (size_t)b * HD * ND + n0;
#pragma unroll 2
    for (int it = 0; it < 8; ++it) {
      int blockid = it * 256 + tid;
      int n4 = (blockid & 15) << 2;
      int k0 = (blockid >> 4) << 2;
      f32x4 v0 = *(const f32x4*)(kb + (size_t)(k0 + 0) * ND + n4);
      f32x4 v1 = *(const f32x4*)(kb + (size_t)(k0 + 1) * ND + n4);
      f32x4 v2 = *(const f32x4*)(kb + (size_t)(k0 + 2) * ND + n4);
      f32x4 v3 = *(const f32x4*)(kb + (size_t)(k0 + 3) * ND + n4);
#pragma unroll
      for (int j = 0; j < 4; ++j) {
        int n = n4 + j;
        half4 hv;
        hv[0] = (_Float16)v0[j]; hv[1] = (_Float16)v1[j];
        hv[2] = (_Float16)v2[j]; hv[3] = (_Float16)v3[j];
        *(half4*)&X[(n << 9) + ((((k0 >> 3) ^ (n & 7)) << 3) + (k0 & 7))] = hv;
      }
    }
  }
  __syncthreads();

  f32x4 acc[4][8];
  const f32x4 z4 = {0.f, 0.f, 0.f, 0.f};

  // ---- stage 1: proj_know = know_tile . Wkb^T + b_kb
#pragma unroll
  for (int mt = 0; mt < 4; ++mt)
#pragma unroll
    for (int ht = 0; ht < 8; ++ht) acc[mt][ht] = z4;
  mfma_stage(X, Wkb16 + (size_t)(w * 128) * HD, acc, c, q);
  __syncthreads();
#pragma unroll
  for (int ht = 0; ht < 8; ++ht) {
    int col = w * 128 + ht * 16 + c;
    float bias = b_kb[col];
#pragma unroll
    for (int mt = 0; mt < 4; ++mt)
#pragma unroll
      for (int r = 0; r < 4; ++r)
        X[xidx(mt * 16 + q * 4 + r, col)] = (_Float16)(acc[mt][ht][r] + bias);
  }
  __syncthreads();

  // ---- stage 2: h = elu(proj_know . Weff_b^T + b_cat)
#pragma unroll
  for (int mt = 0; mt < 4; ++mt)
#pragma unroll
    for (int ht = 0; ht < 8; ++ht) acc[mt][ht] = z4;
  mfma_stage(X, Weff16 + ((size_t)b * HD + w * 128) * HD, acc, c, q);
  __syncthreads();
#pragma unroll
  for (int ht = 0; ht < 8; ++ht) {
    int col = w * 128 + ht * 16 + c;
    float bias = b_cat[col];
#pragma unroll
    for (int mt = 0; mt < 4; ++mt)
#pragma unroll
      for (int r = 0; r < 4; ++r) {
        float v = acc[mt][ht][r] + bias;
        v = v > 0.f ? v : expm1f(v);
        X[xidx(mt * 16 + q * 4 + r, col)] = (_Float16)v;
      }
  }
  __syncthreads();

  // ---- stage 3: h2 = h . Wcat2^T + b_cat2; attn = elu(h2*ctl); logits = attn . W_attn
#pragma unroll
  for (int mt = 0; mt < 4; ++mt)
#pragma unroll
    for (int ht = 0; ht < 8; ++ht) acc[mt][ht] = z4;
  mfma_stage(X, Wc216 + (size_t)(w * 128) * HD, acc, c, q);

  float ll[4][4];
#pragma unroll
  for (int mt = 0; mt < 4; ++mt)
#pragma unroll
    for (int r = 0; r < 4; ++r) ll[mt][r] = 0.f;
  const float* ctl = control + (size_t)(3 * NB + b) * HD;
#pragma unroll
  for (int ht = 0; ht < 8; ++ht) {
    int col = w * 128 + ht * 16 + c;
    float bias = b_cat2[col];
    float cv = ctl[col];
    float wa = W_attn[col];
#pragma unroll
    for (int mt = 0; mt < 4; ++mt)
#pragma unroll
      for (int r = 0; r < 4; ++r) {
        float h2 = acc[mt][ht][r] + bias;
        float at = h2 * cv;
        at = at > 0.f ? at : expm1f(at);
        ll[mt][r] += at * wa;
      }
  }
  // reduce across the 16 col-lanes
#pragma unroll
  for (int off = 1; off <= 8; off <<= 1)
#pragma unroll
    for (int mt = 0; mt < 4; ++mt)
#pragma unroll
      for (int r = 0; r < 4; ++r) ll[mt][r] += __shfl_xor(ll[mt][r], off);

  // cross-wave reduction via LDS (X reuse)
  __syncthreads();
  float* pr = (float*)X;
  if (c == 0) {
#pragma unroll
    for (int mt = 0; mt < 4; ++mt)
#pragma unroll
      for (int r = 0; r < 4; ++r)
        pr[w * 64 + mt * 16 + q * 4 + r] = ll[mt][r];
  }
  __syncthreads();
  if (tid < 64) {
    float s = pr[tid] + pr[64 + tid] + pr[128 + tid] + pr[192 + tid];
    logits[(size_t)b * ND + n0 + tid] = s;
  }
}

// K4: softmax over n per b (b_attn is a uniform shift -> dropped)
__global__ __launch_bounds__(256) void softmax_k(const float* __restrict__ logits,
                                                 float* __restrict__ a) {
  int b = blockIdx.x, tid = threadIdx.x;
  __shared__ float red[4];
  const float* l = logits + (size_t)b * ND;
  float* av = a + (size_t)b * ND;
  float m = -1e30f;
  for (int i = tid; i < ND; i += 256) m = fmaxf(m, l[i]);
#pragma unroll
  for (int off = 32; off; off >>= 1) m = fmaxf(m, __shfl_xor(m, off));
  if ((tid & 63) == 0) red[tid >> 6] = m;
  __syncthreads();
  float M = fmaxf(fmaxf(red[0], red[1]), fmaxf(red[2], red[3]));
  __syncthreads();
  float s = 0.f;
  for (int i = tid; i < ND; i += 256) {
    float e = expf(l[i] - M);
    av[i] = e;
    s += e;
  }
#pragma unroll
  for (int off = 32; off; off >>= 1) s += __shfl_xor(s, off);
  if ((tid & 63) == 0) red[tid >> 6] = s;
  __syncthreads();
  float inv = 1.f / (red[0] + red[1] + red[2] + red[3]);
  for (int i = tid; i < ND; i += 256) av[i] *= inv;
}

// K5: read[b][kk] = sum_n a[b][n] * know[b][kk][n]  (full f32)
__global__ __launch_bounds__(256) void read_k(const float* __restrict__ know,
                                              const float* __restrict__ a,
                                              float* __restrict__ out) {
  int b = blockIdx.x >> 7;
  int kk = ((blockIdx.x & 127) << 2) + (threadIdx.x >> 6);
  int lane = threadIdx.x & 63;
  const f32x4* kr = (const f32x4*)(know + ((size_t)b * HD + kk) * ND);
  const f32x4* ar = (const f32x4*)(a + (size_t)b * ND);
  float s = 0.f;
#pragma unroll
  for (int i = lane; i < 512; i += 64) {
    f32x4 kv = kr[i];
    f32x4 av = ar[i];
    s += kv[0] * av[0] + kv[1] * av[1] + kv[2] * av[2] + kv[3] * av[3];
  }
#pragma unroll
  for (int off = 32; off; off >>= 1) s += __shfl_xor(s, off);
  if (lane == 0) out[(size_t)b * HD + kk] = s;
}

extern "C" void kernel_launch(void* const* d_in, const int* in_sizes, int n_in,
                              void* d_out, int out_size, void* d_ws, size_t ws_size,
                              hipStream_t stream) {
  const float* memory = (const float*)d_in[0];
  const float* know = (const float*)d_in[1];
  const float* control = (const float*)d_in[2];
  const float* masks = (const float*)d_in[3];
  const float* W_mem = (const float*)d_in[4];
  const float* b_mem = (const float*)d_in[5];
  const float* W_kb = (const float*)d_in[6];
  const float* b_kb = (const float*)d_in[7];
  const float* W_cat = (const float*)d_in[8];
  const float* b_cat = (const float*)d_in[9];
  const float* W_cat2 = (const float*)d_in[10];
  const float* b_cat2 = (const float*)d_in[11];
  const float* W_attn = (const float*)d_in[12];
  // d_in[13] = b_attn: uniform logit shift, softmax-invariant.

  char* ws = (char*)d_ws;
  _Float16* Wkb16 = (_Float16*)(ws);                 //   512*512*2 = 524288
  _Float16* Wc216 = (_Float16*)(ws + 524288);        //   524288
  _Float16* Weff16 = (_Float16*)(ws + 1048576);      //   32*512*512*2 = 16777216
  float* pm = (float*)(ws + 17825792);               //   65536
  float* logits = (float*)(ws + 17891328);           //   262144
  float* aprob = (float*)(ws + 18153472);            //   262144  (total ~17.6 MB)
  float* out = (float*)d_out;

  hipLaunchKernelGGL(projmem_k, dim3(32), dim3(256), 0, stream,
                     memory, masks, W_mem, b_mem, pm);
  hipLaunchKernelGGL(prep_k, dim3(4352), dim3(256), 0, stream,
                     W_kb, W_cat2, W_cat, pm, Wkb16, Wc216, Weff16);
  hipLaunchKernelGGL(fused_main, dim3(1024), dim3(256), 0, stream,
                     know, control, Wkb16, Weff16, Wc216,
                     b_kb, b_cat, b_cat2, W_attn, logits);
  hipLaunchKernelGGL(softmax_k, dim3(32), dim3(256), 0, stream, logits, aprob);
  hipLaunchKernelGGL(read_k, dim3(4096), dim3(256), 0, stream, know, aprob, out);
}

// Round 4
// 454.919 us; speedup vs baseline: 1.3454x; 1.2497x over previous
//
#include <hip/hip_runtime.h>
#include <hip/hip_bf16.h>
#include <cmath>

#define HD 512
#define ND 2048
#define NB 32
#define NT 128   // n-rows per workgroup (8 waves x 64 output cols each)

typedef _Float16 half8 __attribute__((ext_vector_type(8)));
typedef _Float16 half4 __attribute__((ext_vector_type(4)));
typedef float f32x4 __attribute__((ext_vector_type(4)));

// XOR-swizzled LDS index for a [NT][HD] fp16 tile with physical stride 512.
__device__ __forceinline__ int xidx(int r, int c) {
  return (r << 9) + (((c >> 3) ^ (r & 7)) << 3) + (c & 7);
}

// One K=512 GEMM stage: D[128 rows][64 cols per wave] += X(128x512,f16,LDS) * Wg^T
// Wg row-major [outdim][512] fp16, offset to this wave's 64-row slice.
// Per ks: 4 global B-frag loads + 8 LDS A-frag loads -> 32 MFMAs.
__device__ __forceinline__ void mfma_stage(const _Float16* Xs,
                                           const _Float16* __restrict__ Wg,
                                           f32x4 (&acc)[8][4], int c, int q) {
  const _Float16* wb = Wg + (size_t)c * HD + q * 8;
#pragma unroll 2
  for (int ks = 0; ks < 16; ++ks) {
    half8 bf[4];
#pragma unroll
    for (int ht = 0; ht < 4; ++ht)
      bf[ht] = *(const half8*)(wb + ht * (16 * HD) + ks * 32);
    half8 a[8];
#pragma unroll
    for (int mt = 0; mt < 8; ++mt)
      a[mt] = *(const half8*)&Xs[((mt * 16 + c) << 9) + ((((ks << 2) + q) ^ (c & 7)) << 3)];
#pragma unroll
    for (int ht = 0; ht < 4; ++ht)
#pragma unroll
      for (int mt = 0; mt < 8; ++mt)
        acc[mt][ht] = __builtin_amdgcn_mfma_f32_16x16x32_f16(a[mt], bf[ht], acc[mt][ht], 0, 0, 0);
  }
}

// K1: proj_mem[b][h] = (memory[3,b,:]*masks[b,:]) . W_mem[h,:] + b_mem[h]
__global__ __launch_bounds__(256) void projmem_k(const float* __restrict__ memory,
                                                 const float* __restrict__ masks,
                                                 const float* __restrict__ W_mem,
                                                 const float* __restrict__ b_mem,
                                                 float* __restrict__ pm) {
  int b = blockIdx.x;
  int tid = threadIdx.x;
  __shared__ float lm[HD];
  for (int i = tid; i < HD; i += 256)
    lm[i] = memory[(size_t)(3 * NB + b) * HD + i] * masks[(size_t)b * HD + i];
  __syncthreads();
  for (int h = tid; h < HD; h += 256) {
    const f32x4* wr = (const f32x4*)(W_mem + (size_t)h * HD);
    const f32x4* lv = (const f32x4*)lm;
    float s = 0.f;
#pragma unroll 4
    for (int k = 0; k < 128; ++k) {
      f32x4 wv = wr[k];
      f32x4 l = lv[k];
      s += wv[0] * l[0] + wv[1] * l[1] + wv[2] * l[2] + wv[3] * l[3];
    }
    pm[(size_t)b * HD + h] = s + b_mem[h];
  }
}

// K2: convert W_kb, W_cat2 to fp16; build Weff[b][h'][h] = pm[b][h]*W_cat[h'][h] + W_cat[h'][512+h]
__global__ __launch_bounds__(256) void prep_k(const float* __restrict__ W_kb,
                                              const float* __restrict__ W_cat2,
                                              const float* __restrict__ W_cat,
                                              const float* __restrict__ pm,
                                              _Float16* __restrict__ Wkb16,
                                              _Float16* __restrict__ Wc216,
                                              _Float16* __restrict__ Weff16) {
  int rowid = blockIdx.x * 4 + (threadIdx.x >> 6);
  int lane = threadIdx.x & 63;
  int h0 = lane * 8;
  half8 o;
  if (rowid < 512) {
    const float* s = W_kb + (size_t)rowid * HD + h0;
    f32x4 v0 = *(const f32x4*)s;
    f32x4 v1 = *(const f32x4*)(s + 4);
#pragma unroll
    for (int j = 0; j < 4; ++j) { o[j] = (_Float16)v0[j]; o[4 + j] = (_Float16)v1[j]; }
    *(half8*)(Wkb16 + (size_t)rowid * HD + h0) = o;
  } else if (rowid < 1024) {
    int r = rowid - 512;
    const float* s = W_cat2 + (size_t)r * HD + h0;
    f32x4 v0 = *(const f32x4*)s;
    f32x4 v1 = *(const f32x4*)(s + 4);
#pragma unroll
    for (int j = 0; j < 4; ++j) { o[j] = (_Float16)v0[j]; o[4 + j] = (_Float16)v1[j]; }
    *(half8*)(Wc216 + (size_t)r * HD + h0) = o;
  } else {
    int r = rowid - 1024;          // r = b*512 + hp
    int b = r >> 9;
    int hp = r & 511;
    const float* wc = W_cat + (size_t)hp * (2 * HD);
    const float* pmb = pm + (size_t)b * HD;
#pragma unroll
    for (int j = 0; j < 8; ++j) {
      int h = h0 + j;
      o[j] = (_Float16)(pmb[h] * wc[h] + wc[HD + h]);
    }
    *(half8*)(Weff16 + (size_t)r * HD + h0) = o;
  }
}

// K3: fused 3-stage GEMM chain + logits. One wg per (b, 128-row n-tile). 8 waves.
// 128 KB LDS -> 1 wg/CU (2 waves/SIMD). launch_bounds(512,2): regs <= 256/wave.
__global__ __launch_bounds__(512, 2) void fused_main(
    const float* __restrict__ know, const float* __restrict__ control,
    const _Float16* __restrict__ Wkb16, const _Float16* __restrict__ Weff16,
    const _Float16* __restrict__ Wc216,
    const float* __restrict__ b_kb, const float* __restrict__ b_cat,
    const float* __restrict__ b_cat2, const float* __restrict__ W_attn,
    float* __restrict__ logits) {
  __shared__ _Float16 X[NT * HD];   // 128 KB, XOR-swizzled [n][h]
  const int tid = threadIdx.x;
  const int w = tid >> 6;           // wave id 0..7: owns cols [64w, 64w+64)
  const int lane = tid & 63;
  const int c = lane & 15;
  const int q = lane >> 4;
  const int b = blockIdx.x >> 4;
  const int n0 = (blockIdx.x & 15) * NT;

  // stage 0: X[n][kk] = (fp16) know[b][kk][n0+n] via 4x4 register-transpose,
  // packed half4 (b64) LDS writes. 4096 4x4 blocks, 8 per thread.
  {
    const float* kb = know + (size_t)b * HD * ND + n0;
#pragma unroll 2
    for (int it = 0; it < 8; ++it) {
      int blockid = it * 512 + tid;
      int n4 = (blockid & 31) << 2;   // 0..124
      int k0 = (blockid >> 5) << 2;   // 0..508
      f32x4 v0 = *(const f32x4*)(kb + (size_t)(k0 + 0) * ND + n4);
      f32x4 v1 = *(const f32x4*)(kb + (size_t)(k0 + 1) * ND + n4);
      f32x4 v2 = *(const f32x4*)(kb + (size_t)(k0 + 2) * ND + n4);
      f32x4 v3 = *(const f32x4*)(kb + (size_t)(k0 + 3) * ND + n4);
#pragma unroll
      for (int j = 0; j < 4; ++j) {
        int n = n4 + j;
        half4 hv;
        hv[0] = (_Float16)v0[j]; hv[1] = (_Float16)v1[j];
        hv[2] = (_Float16)v2[j]; hv[3] = (_Float16)v3[j];
        *(half4*)&X[(n << 9) + ((((k0 >> 3) ^ (n & 7)) << 3) + (k0 & 7))] = hv;
      }
    }
  }
  __syncthreads();

  f32x4 acc[8][4];
  const f32x4 z4 = {0.f, 0.f, 0.f, 0.f};

  // ---- stage 1: proj_know = know_tile . Wkb^T + b_kb
#pragma unroll
  for (int mt = 0; mt < 8; ++mt)
#pragma unroll
    for (int ht = 0; ht < 4; ++ht) acc[mt][ht] = z4;
  mfma_stage(X, Wkb16 + (size_t)(w * 64) * HD, acc, c, q);
  __syncthreads();
#pragma unroll
  for (int ht = 0; ht < 4; ++ht) {
    int col = w * 64 + ht * 16 + c;
    float bias = b_kb[col];
#pragma unroll
    for (int mt = 0; mt < 8; ++mt)
#pragma unroll
      for (int r = 0; r < 4; ++r)
        X[xidx(mt * 16 + q * 4 + r, col)] = (_Float16)(acc[mt][ht][r] + bias);
  }
  __syncthreads();

  // ---- stage 2: h = elu(proj_know . Weff_b^T + b_cat)
#pragma unroll
  for (int mt = 0; mt < 8; ++mt)
#pragma unroll
    for (int ht = 0; ht < 4; ++ht) acc[mt][ht] = z4;
  mfma_stage(X, Weff16 + ((size_t)b * HD + w * 64) * HD, acc, c, q);
  __syncthreads();
#pragma unroll
  for (int ht = 0; ht < 4; ++ht) {
    int col = w * 64 + ht * 16 + c;
    float bias = b_cat[col];
#pragma unroll
    for (int mt = 0; mt < 8; ++mt)
#pragma unroll
      for (int r = 0; r < 4; ++r) {
        float v = acc[mt][ht][r] + bias;
        v = v > 0.f ? v : expm1f(v);
        X[xidx(mt * 16 + q * 4 + r, col)] = (_Float16)v;
      }
  }
  __syncthreads();

  // ---- stage 3: h2 = h . Wcat2^T + b_cat2; attn = elu(h2*ctl); logits = attn . W_attn
#pragma unroll
  for (int mt = 0; mt < 8; ++mt)
#pragma unroll
    for (int ht = 0; ht < 4; ++ht) acc[mt][ht] = z4;
  mfma_stage(X, Wc216 + (size_t)(w * 64) * HD, acc, c, q);

  float ll[8][4];
#pragma unroll
  for (int mt = 0; mt < 8; ++mt)
#pragma unroll
    for (int r = 0; r < 4; ++r) ll[mt][r] = 0.f;
  const float* ctl = control + (size_t)(3 * NB + b) * HD;
#pragma unroll
  for (int ht = 0; ht < 4; ++ht) {
    int col = w * 64 + ht * 16 + c;
    float bias = b_cat2[col];
    float cv = ctl[col];
    float wa = W_attn[col];
#pragma unroll
    for (int mt = 0; mt < 8; ++mt)
#pragma unroll
      for (int r = 0; r < 4; ++r) {
        float h2 = acc[mt][ht][r] + bias;
        float at = h2 * cv;
        at = at > 0.f ? at : expm1f(at);
        ll[mt][r] += at * wa;
      }
  }
  // reduce across the 16 col-lanes (xor offsets touch only lane bits 0..3)
#pragma unroll
  for (int off = 1; off <= 8; off <<= 1)
#pragma unroll
    for (int mt = 0; mt < 8; ++mt)
#pragma unroll
      for (int r = 0; r < 4; ++r) ll[mt][r] += __shfl_xor(ll[mt][r], off);

  // cross-wave reduction via LDS (X reuse): pr[8 waves][128 rows]
  __syncthreads();
  float* pr = (float*)X;
  if (c == 0) {
#pragma unroll
    for (int mt = 0; mt < 8; ++mt)
#pragma unroll
      for (int r = 0; r < 4; ++r)
        pr[w * NT + mt * 16 + q * 4 + r] = ll[mt][r];
  }
  __syncthreads();
  if (tid < NT) {
    float s = 0.f;
#pragma unroll
    for (int ww = 0; ww < 8; ++ww) s += pr[ww * NT + tid];
    logits[(size_t)b * ND + n0 + tid] = s;
  }
}

// K4: softmax over n per b (b_attn is a uniform shift -> dropped)
__global__ __launch_bounds__(256) void softmax_k(const float* __restrict__ logits,
                                                 float* __restrict__ a) {
  int b = blockIdx.x, tid = threadIdx.x;
  __shared__ float red[4];
  const float* l = logits + (size_t)b * ND;
  float* av = a + (size_t)b * ND;
  float m = -1e30f;
  for (int i = tid; i < ND; i += 256) m = fmaxf(m, l[i]);
#pragma unroll
  for (int off = 32; off; off >>= 1) m = fmaxf(m, __shfl_xor(m, off));
  if ((tid & 63) == 0) red[tid >> 6] = m;
  __syncthreads();
  float M = fmaxf(fmaxf(red[0], red[1]), fmaxf(red[2], red[3]));
  __syncthreads();
  float s = 0.f;
  for (int i = tid; i < ND; i += 256) {
    float e = expf(l[i] - M);
    av[i] = e;
    s += e;
  }
#pragma unroll
  for (int off = 32; off; off >>= 1) s += __shfl_xor(s, off);
  if ((tid & 63) == 0) red[tid >> 6] = s;
  __syncthreads();
  float inv = 1.f / (red[0] + red[1] + red[2] + red[3]);
  for (int i = tid; i < ND; i += 256) av[i] *= inv;
}

// K5: read[b][kk] = sum_n a[b][n] * know[b][kk][n]  (full f32)
__global__ __launch_bounds__(256) void read_k(const float* __restrict__ know,
                                              const float* __restrict__ a,
                                              float* __restrict__ out) {
  int b = blockIdx.x >> 7;
  int kk = ((blockIdx.x & 127) << 2) + (threadIdx.x >> 6);
  int lane = threadIdx.x & 63;
  const f32x4* kr = (const f32x4*)(know + ((size_t)b * HD + kk) * ND);
  const f32x4* ar = (const f32x4*)(a + (size_t)b * ND);
  float s = 0.f;
#pragma unroll
  for (int i = lane; i < 512; i += 64) {
    f32x4 kv = kr[i];
    f32x4 av = ar[i];
    s += kv[0] * av[0] + kv[1] * av[1] + kv[2] * av[2] + kv[3] * av[3];
  }
#pragma unroll
  for (int off = 32; off; off >>= 1) s += __shfl_xor(s, off);
  if (lane == 0) out[(size_t)b * HD + kk] = s;
}

extern "C" void kernel_launch(void* const* d_in, const int* in_sizes, int n_in,
                              void* d_out, int out_size, void* d_ws, size_t ws_size,
                              hipStream_t stream) {
  const float* memory = (const float*)d_in[0];
  const float* know = (const float*)d_in[1];
  const float* control = (const float*)d_in[2];
  const float* masks = (const float*)d_in[3];
  const float* W_mem = (const float*)d_in[4];
  const float* b_mem = (const float*)d_in[5];
  const float* W_kb = (const float*)d_in[6];
  const float* b_kb = (const float*)d_in[7];
  const float* W_cat = (const float*)d_in[8];
  const float* b_cat = (const float*)d_in[9];
  const float* W_cat2 = (const float*)d_in[10];
  const float* b_cat2 = (const float*)d_in[11];
  const float* W_attn = (const float*)d_in[12];
  // d_in[13] = b_attn: uniform logit shift, softmax-invariant.

  char* ws = (char*)d_ws;
  _Float16* Wkb16 = (_Float16*)(ws);                 //   512*512*2 = 524288
  _Float16* Wc216 = (_Float16*)(ws + 524288);        //   524288
  _Float16* Weff16 = (_Float16*)(ws + 1048576);      //   32*512*512*2 = 16777216
  float* pm = (float*)(ws + 17825792);               //   65536
  float* logits = (float*)(ws + 17891328);           //   262144
  float* aprob = (float*)(ws + 18153472);            //   262144  (total ~17.6 MB)
  float* out = (float*)d_out;

  hipLaunchKernelGGL(projmem_k, dim3(32), dim3(256), 0, stream,
                     memory, masks, W_mem, b_mem, pm);
  hipLaunchKernelGGL(prep_k, dim3(4352), dim3(256), 0, stream,
                     W_kb, W_cat2, W_cat, pm, Wkb16, Wc216, Weff16);
  hipLaunchKernelGGL(fused_main, dim3(512), dim3(512), 0, stream,
                     know, control, Wkb16, Weff16, Wc216,
                     b_kb, b_cat, b_cat2, W_attn, logits);
  hipLaunchKernelGGL(softmax_k, dim3(32), dim3(256), 0, stream, logits, aprob);
  hipLaunchKernelGGL(read_k, dim3(4096), dim3(256), 0, stream, know, aprob, out);
}